// Round 4
// baseline (342.402 us; speedup 1.0000x reference)
//
#include <hip/hip_runtime.h>
#include <math.h>

#define IN_CH 128
#define OUT_CH 16
#define NXCD 8
#define B 256
#define CHUNK 2048        // edges per grabbed chunk
#define CTR_STRIDE 64     // ints between counters (256B) — avoid cross-XCD line sharing

// ---------------- helpers ----------------

__device__ __forceinline__ int xcc_id() {
    int x;
    asm volatile("s_getreg_b32 %0, hwreg(HW_REG_XCC_ID, 0, 32)" : "=s"(x));
    return x & (NXCD - 1);
}
__device__ __forceinline__ void atomAddWG(float* p, float v) {
    __hip_atomic_fetch_add(p, v, __ATOMIC_RELAXED, __HIP_MEMORY_SCOPE_WORKGROUP);
}
__device__ __forceinline__ int ctrGrab(int* p, bool local) {
    if (local) return __hip_atomic_fetch_add(p, 1, __ATOMIC_RELAXED, __HIP_MEMORY_SCOPE_WORKGROUP);
    return atomicAdd(p, 1);
}

// ---------------- zero ----------------

__global__ void k_zero4(float4* p, long long n4) {
    long long stride = (long long)gridDim.x * blockDim.x;
    for (long long i = (long long)blockIdx.x * blockDim.x + threadIdx.x; i < n4; i += stride)
        p[i] = make_float4(0.f, 0.f, 0.f, 0.f);
}

// ---------------- owner key: key[e] = (col[e]>>5) & 7 ----------------

__global__ void k_prep(const int* __restrict__ col, unsigned char* __restrict__ key, int E) {
    int stride = gridDim.x * blockDim.x;
    for (int e = blockIdx.x * blockDim.x + threadIdx.x; e < E; e += stride)
        key[e] = (unsigned char)((col[e] >> 5) & (NXCD - 1));
}

// ---------------- degree accumulation (owner-sliced, L2-local atomics) ----------------

template <bool LOCAL>
__global__ void k_deg(const unsigned char* __restrict__ key, const int* __restrict__ col,
                      const float* __restrict__ ew, float* __restrict__ deg,
                      int* __restrict__ ctrs, int E) {
    int p = LOCAL ? xcc_id() : 0;
    int* ctr = ctrs + p * CTR_STRIDE;
    int nch = (E + CHUNK - 1) / CHUNK;
    __shared__ int s_chunk;
    for (;;) {
        if (threadIdx.x == 0) s_chunk = ctrGrab(ctr, LOCAL);
        __syncthreads();
        int c = s_chunk;
        __syncthreads();
        if (c >= nch) break;
        int base = c * CHUNK;
        int end = base + CHUNK < E ? base + CHUNK : E;
        for (int e = base + threadIdx.x; e < end; e += B) {
            if (!LOCAL || key[e] == p) {
                if (LOCAL) atomAddWG(&deg[col[e]], ew[e]);
                else       atomicAdd(&deg[col[e]], ew[e]);
            }
        }
    }
}

// dinv = rsqrt(1 + deg); selfnorm = dinv^2
__global__ void k_dinv(const float* __restrict__ deg, float* __restrict__ dinv,
                       float* __restrict__ selfnorm, int N) {
    int i = blockIdx.x * blockDim.x + threadIdx.x;
    if (i >= N) return;
    float r = rsqrtf(1.0f + deg[i]);
    dinv[i] = r;
    selfnorm[i] = r * r;
}

// ---------------- projection: h0 = x @ W^T ----------------

__global__ void k_proj(const float* __restrict__ x, const float* __restrict__ W,
                       float* __restrict__ y, int N) {
    __shared__ float sW[OUT_CH * (IN_CH + 1)];
    for (int i = threadIdx.x; i < OUT_CH * IN_CH; i += blockDim.x) {
        int o = i >> 7, k = i & 127;
        sW[o * (IN_CH + 1) + k] = W[i];
    }
    __syncthreads();
    int t = threadIdx.x;
    int n = blockIdx.x * 16 + (t >> 4);
    int o = t & 15;
    if (n >= N) return;
    const float* xr = x + (size_t)n * IN_CH;
    const float* wr = sW + o * (IN_CH + 1);
    float acc = 0.0f;
#pragma unroll
    for (int k = 0; k < IN_CH; k += 4) {
        float4 xv = *reinterpret_cast<const float4*>(xr + k);
        acc += xv.x * wr[k] + xv.y * wr[k + 1] + xv.z * wr[k + 2] + xv.w * wr[k + 3];
    }
    y[(size_t)n * OUT_CH + o] = acc;
}

// ---------------- scatter hop (owner-sliced, ballot-compacted) ----------------
// hc[cl][ch] += dinv[r]*ew*dinv[cl] * hin[r][ch]  for edges owned by this XCD

template <bool LOCAL>
__global__ void __launch_bounds__(B)
k_scat(const unsigned char* __restrict__ key, const int* __restrict__ row,
       const int* __restrict__ col, const float* __restrict__ ew,
       const float* __restrict__ dinv, const float* __restrict__ hin,
       float* __restrict__ hc, int* __restrict__ ctrs, int E) {
    int p = LOCAL ? xcc_id() : 0;
    int* ctr = ctrs + p * CTR_STRIDE;
    int nch = (E + CHUNK - 1) / CHUNK;
    __shared__ int s_chunk, s_n, s_wbase[B / 64];
    __shared__ int s_eid[B];
    int tid = threadIdx.x;
    for (;;) {
        if (tid == 0) s_chunk = ctrGrab(ctr, LOCAL);
        __syncthreads();
        int c = s_chunk;
        __syncthreads();
        if (c >= nch) break;
        int base = c * CHUNK;
        int end = base + CHUNK < E ? base + CHUNK : E;
        for (int t = base; t < end; t += B) {
            int e = t + tid;
            bool match = (e < end) && (!LOCAL || key[e] == p);
            if (tid == 0) s_n = 0;
            __syncthreads();
            unsigned long long m = __ballot(match);
            if ((tid & 63) == 0) s_wbase[tid >> 6] = atomicAdd(&s_n, __popcll(m));
            __syncthreads();
            if (match) {
                int pos = s_wbase[tid >> 6] + __popcll(m & ((1ull << (tid & 63)) - 1ull));
                s_eid[pos] = e;
            }
            __syncthreads();
            int n = s_n;
            for (int j = tid; j < n * OUT_CH; j += B) {
                int e2 = s_eid[j >> 4];
                int ch = j & 15;
                int r = row[e2], cl = col[e2];
                float nv = dinv[r] * ew[e2] * dinv[cl];
                float v = nv * hin[(size_t)r * OUT_CH + ch];
                if (LOCAL) atomAddWG(&hc[(size_t)cl * OUT_CH + ch], v);
                else       atomicAdd(&hc[(size_t)cl * OUT_CH + ch], v);
            }
        }
    }
}

// ---------------- hop1 reduce: h1 = self*h0 + hc; re-zero hc ----------------

__global__ void k_red1(const float* __restrict__ hin, const float* __restrict__ self,
                       float* __restrict__ hc, float* __restrict__ hout, int N) {
    int i4 = blockIdx.x * blockDim.x + threadIdx.x;
    int n4 = N * (OUT_CH / 4);
    if (i4 >= n4) return;
    float4 a = reinterpret_cast<const float4*>(hin)[i4];
    float s = self[i4 >> 2];
    float4 h = reinterpret_cast<const float4*>(hc)[i4];
    a.x = a.x * s + h.x; a.y = a.y * s + h.y;
    a.z = a.z * s + h.z; a.w = a.w * s + h.w;
    reinterpret_cast<float4*>(hc)[i4] = make_float4(0.f, 0.f, 0.f, 0.f);
    reinterpret_cast<float4*>(hout)[i4] = a;
}

// ---------------- hop2 reduce fused with log_softmax ----------------

__global__ void k_red2_lsm(const float* __restrict__ hin, const float* __restrict__ self,
                           const float* __restrict__ hc, float* __restrict__ out, int N) {
    int n = blockIdx.x * blockDim.x + threadIdx.x;
    if (n >= N) return;
    size_t base = (size_t)n * OUT_CH;
    float s = self[n];
    float v[OUT_CH];
    float4* vv = reinterpret_cast<float4*>(v);
#pragma unroll
    for (int q = 0; q < 4; ++q) {
        float4 a = reinterpret_cast<const float4*>(hin + base)[q];
        float4 h = reinterpret_cast<const float4*>(hc + base)[q];
        vv[q] = make_float4(a.x * s + h.x, a.y * s + h.y, a.z * s + h.z, a.w * s + h.w);
    }
    float m = v[0];
#pragma unroll
    for (int i = 1; i < OUT_CH; i++) m = fmaxf(m, v[i]);
    float sum = 0.0f;
#pragma unroll
    for (int i = 0; i < OUT_CH; i++) sum += expf(v[i] - m);
    float lse = m + logf(sum);
    float* orow = out + base;
#pragma unroll
    for (int i = 0; i < OUT_CH; i++) orow[i] = v[i] - lse;
}

// ---------------- launch ----------------

extern "C" void kernel_launch(void* const* d_in, const int* in_sizes, int n_in,
                              void* d_out, int out_size, void* d_ws, size_t ws_size,
                              hipStream_t stream) {
    const float* x  = (const float*)d_in[0];
    const float* W  = (const float*)d_in[1];
    const float* ew = (const float*)d_in[2];
    const int*   ei = (const int*)d_in[3];  // harness pushes int64 as int32

    int N = in_sizes[0] / IN_CH;
    int E = in_sizes[2];
    const int* row = ei;       // source
    const int* col = ei + E;   // target

    auto al = [](size_t v) { return (v + 255) & ~(size_t)255; };
    size_t N16 = (size_t)N * OUT_CH;

    size_t o_key  = 0;
    size_t o_dinv = o_key  + al((size_t)E);
    size_t o_self = o_dinv + al((size_t)N * 4);
    size_t o_h0   = o_self + al((size_t)N * 4);
    size_t o_h1   = o_h0   + al(N16 * 4);
    size_t o_deg  = o_h1   + al(N16 * 4);        // zero region starts here
    size_t o_hc   = o_deg  + al((size_t)N * 4);
    size_t o_cnt  = o_hc   + al(N16 * 4);
    size_t need   = o_cnt  + al((size_t)3 * NXCD * CTR_STRIDE * 4);
    bool local = (need <= ws_size);  // should always hold (~12 MB)

    char* ws = (char*)d_ws;
    unsigned char* key = (unsigned char*)(ws + o_key);
    float* dinv     = (float*)(ws + o_dinv);
    float* selfnorm = (float*)(ws + o_self);
    float* h0       = (float*)(ws + o_h0);
    float* h1       = (float*)(ws + o_h1);
    float* deg      = (float*)(ws + o_deg);
    float* hc       = (float*)(ws + o_hc);
    int*   cnt      = (int*)(ws + o_cnt);
    int*   ctr_deg  = cnt;
    int*   ctr_s1   = cnt + NXCD * CTR_STRIDE;
    int*   ctr_s2   = cnt + 2 * NXCD * CTR_STRIDE;

    // 1) zero deg..counters (contiguous)
    long long z4 = (long long)(need - o_deg) / 16;
    int gz = (int)((z4 + B - 1) / B);
    if (gz > 2048) gz = 2048;
    k_zero4<<<gz, B, 0, stream>>>((float4*)(ws + o_deg), z4);

    // 2) owner keys
    k_prep<<<1024, B, 0, stream>>>(col, key, E);

    // 3) degree accumulation
    if (local) k_deg<true ><<<2048, B, 0, stream>>>(key, col, ew, deg, ctr_deg, E);
    else       k_deg<false><<<2048, B, 0, stream>>>(key, col, ew, deg, ctr_deg, E);

    // 4) dinv + selfnorm
    k_dinv<<<(N + B - 1) / B, B, 0, stream>>>(deg, dinv, selfnorm, N);

    // 5) projection: h0 = x @ W^T
    k_proj<<<(N + 15) / 16, B, 0, stream>>>(x, W, h0, N);

    // 6) hop 1: scatter + reduce (re-zeros hc)
    if (local) k_scat<true ><<<2048, B, 0, stream>>>(key, row, col, ew, dinv, h0, hc, ctr_s1, E);
    else       k_scat<false><<<2048, B, 0, stream>>>(key, row, col, ew, dinv, h0, hc, ctr_s1, E);
    int g4 = (int)((N16 / 4 + B - 1) / B);
    k_red1<<<g4, B, 0, stream>>>(h0, selfnorm, hc, h1, N);

    // 7) hop 2: scatter + reduce fused with log_softmax
    if (local) k_scat<true ><<<2048, B, 0, stream>>>(key, row, col, ew, dinv, h1, hc, ctr_s2, E);
    else       k_scat<false><<<2048, B, 0, stream>>>(key, row, col, ew, dinv, h1, hc, ctr_s2, E);
    k_red2_lsm<<<(N + B - 1) / B, B, 0, stream>>>(h1, selfnorm, hc, (float*)d_out, N);
}